// Round 2
// baseline (481.409 us; speedup 1.0000x reference)
//
#include <hip/hip_runtime.h>
#include <cmath>
#include <climits>

#define EMBED 64
#define KTOP 11        // top_n + 1 (self match included, dropped at output)
#define NB   1024
#define BLOCK 256
#define NWAVE (BLOCK / 64)

// Insert (v,i) into per-thread sorted top-KTOP list (desc value, asc index).
// Fast path: one compare against current min.
__device__ __forceinline__ void topk_insert(float (&vals)[KTOP], int (&idxs)[KTOP],
                                            float v, int i) {
  float last = vals[KTOP - 1];
  if (v < last) return;
  if (v == last && i >= idxs[KTOP - 1]) return;
  float cv = v; int ci = i;
#pragma unroll
  for (int j = 0; j < KTOP; ++j) {
    bool better = (cv > vals[j]) || (cv == vals[j] && ci < idxs[j]);
    if (better) {
      float tv = vals[j]; int ti = idxs[j];
      vals[j] = cv; idxs[j] = ci;
      cv = tv; ci = ti;
    }
  }
}

// Merge 64 lanes' sorted top-KTOP lists into wave top-KTOP, written to LDS.
__device__ __forceinline__ void wave_merge(float (&vals)[KTOP], int (&idxs)[KTOP],
                                           float* wv, int* wi, int lane) {
#pragma unroll
  for (int round = 0; round < KTOP; ++round) {
    float v = vals[0]; int i = idxs[0]; int l = lane;
#pragma unroll
    for (int off = 32; off > 0; off >>= 1) {
      float ov = __shfl_xor(v, off, 64);
      int   oi = __shfl_xor(i, off, 64);
      int   ol = __shfl_xor(l, off, 64);
      if (ov > v || (ov == v && oi < i)) { v = ov; i = oi; l = ol; }
    }
    if (l == lane) {  // I won: pop my head
#pragma unroll
      for (int j = 0; j < KTOP - 1; ++j) { vals[j] = vals[j + 1]; idxs[j] = idxs[j + 1]; }
      vals[KTOP - 1] = -INFINITY; idxs[KTOP - 1] = INT_MAX;
    }
    if (lane == 0) { wv[round] = v; wi[round] = i; }
  }
}

__global__ __launch_bounds__(BLOCK) void sim_pass1(
    const float* __restrict__ emb, const int* __restrict__ user_id,
    float* __restrict__ cand_val, int* __restrict__ cand_idx, int V) {
  __shared__ float t[EMBED];
  __shared__ float wv[NWAVE * KTOP];
  __shared__ int   wi[NWAVE * KTOP];

  const int lane = threadIdx.x & 63;
  const int wid  = threadIdx.x >> 6;

  const int uid = *user_id;
  if (threadIdx.x < EMBED) t[threadIdx.x] = emb[(size_t)uid * EMBED + threadIdx.x];
  __syncthreads();

  // Each lane only ever needs one target chunk: chunk (lane & 15).
  const float4 tgt = ((const float4*)t)[lane & 15];

  float vals[KTOP]; int idxs[KTOP];
#pragma unroll
  for (int j = 0; j < KTOP; ++j) { vals[j] = -INFINITY; idxs[j] = INT_MAX; }

  // Wave-tile loop: each wave reads a 64-row (16 KB) tile as 16 contiguous
  // 1 KB instructions. At step t, lane l loads float4 #(t*64+l) of the tile,
  // which is row t*4+(l>>4), chunk (l&15). Perfect intra-instruction
  // coalescing (64 lanes x 16 B = one contiguous 1 KB segment).
  const int gw = blockIdx.x * NWAVE + wid;
  const int nW = NB * NWAVE;
  const int nTiles = (V + 63) >> 6;

  for (int tile = gw; tile < nTiles; tile += nW) {
    const int rowBase = tile << 6;
    const float4* p = (const float4*)(emb + (size_t)rowBase * EMBED);
#pragma unroll
    for (int t16 = 0; t16 < 16; ++t16) {
      const int row = rowBase + t16 * 4 + (lane >> 4);
      float dot = 0.f, nr = 0.f;
      if (row < V) {
        float4 v = p[t16 * 64 + lane];
        dot = fmaf(v.x, tgt.x, dot); dot = fmaf(v.y, tgt.y, dot);
        dot = fmaf(v.z, tgt.z, dot); dot = fmaf(v.w, tgt.w, dot);
        nr  = fmaf(v.x, v.x, nr);    nr  = fmaf(v.y, v.y, nr);
        nr  = fmaf(v.z, v.z, nr);    nr  = fmaf(v.w, v.w, nr);
      }
      // Reduce dot/norm across the 16-lane group (xor 1,2,4,8 stays in-group).
#pragma unroll
      for (int off = 1; off < 16; off <<= 1) {
        dot += __shfl_xor(dot, off, 64);
        nr  += __shfl_xor(nr,  off, 64);
      }
      // One lane per 16-lane group inserts; condition rotates with t16 so
      // every lane does exactly one insert per tile (balanced lists).
      if ((lane & 15) == t16 && row < V) {
        float sim = dot / sqrtf(nr);   // /||target|| deferred (positive scale)
        topk_insert(vals, idxs, sim, row);
      }
    }
  }

  wave_merge(vals, idxs, &wv[wid * KTOP], &wi[wid * KTOP], lane);
  __syncthreads();

  if (wid == 0) {  // wave 0 merges NWAVE*KTOP entries -> block top-KTOP
    float v = (lane < NWAVE * KTOP) ? wv[lane] : -INFINITY;
    int   i = (lane < NWAVE * KTOP) ? wi[lane] : INT_MAX;
#pragma unroll
    for (int round = 0; round < KTOP; ++round) {
      float bv = v; int bi = i; int bl = lane;
#pragma unroll
      for (int off = 32; off > 0; off >>= 1) {
        float ov = __shfl_xor(bv, off, 64);
        int   oi = __shfl_xor(bi, off, 64);
        int   ol = __shfl_xor(bl, off, 64);
        if (ov > bv || (ov == bv && oi < bi)) { bv = ov; bi = oi; bl = ol; }
      }
      if (bl == lane) { v = -INFINITY; i = INT_MAX; }
      if (lane == 0) {
        cand_val[blockIdx.x * KTOP + round] = bv;
        cand_idx[blockIdx.x * KTOP + round] = bi;
      }
    }
  }
}

__global__ __launch_bounds__(BLOCK) void sim_pass2(
    const float* __restrict__ emb, const int* __restrict__ user_id,
    const float* __restrict__ cand_val, const int* __restrict__ cand_idx,
    float* __restrict__ out, int topn, int ncand) {
  __shared__ float wv[NWAVE * KTOP];
  __shared__ int   wi[NWAVE * KTOP];
  __shared__ float s_nt;

  const int lane = threadIdx.x & 63;
  const int wid  = threadIdx.x >> 6;

  if (wid == 0) {  // compute ||target|| on wave 0
    const int uid = *user_id;
    float x = (lane < EMBED) ? emb[(size_t)uid * EMBED + lane] : 0.f;
    float s = x * x;
#pragma unroll
    for (int off = 32; off > 0; off >>= 1) s += __shfl_xor(s, off, 64);
    if (lane == 0) s_nt = sqrtf(s);
  }

  float vals[KTOP]; int idxs[KTOP];
#pragma unroll
  for (int j = 0; j < KTOP; ++j) { vals[j] = -INFINITY; idxs[j] = INT_MAX; }

  for (int c = threadIdx.x; c < ncand; c += BLOCK)
    topk_insert(vals, idxs, cand_val[c], cand_idx[c]);

  wave_merge(vals, idxs, &wv[wid * KTOP], &wi[wid * KTOP], lane);
  __syncthreads();

  if (wid == 0) {
    float v = (lane < NWAVE * KTOP) ? wv[lane] : -INFINITY;
    int   i = (lane < NWAVE * KTOP) ? wi[lane] : INT_MAX;
    const float nt = s_nt;
#pragma unroll
    for (int round = 0; round < KTOP; ++round) {
      float bv = v; int bi = i; int bl = lane;
#pragma unroll
      for (int off = 32; off > 0; off >>= 1) {
        float ov = __shfl_xor(bv, off, 64);
        int   oi = __shfl_xor(bi, off, 64);
        int   ol = __shfl_xor(bl, off, 64);
        if (ov > bv || (ov == bv && oi < bi)) { bv = ov; bi = oi; bl = ol; }
      }
      if (bl == lane) { v = -INFINITY; i = INT_MAX; }
      // round 0 is the self match -> dropped (matches ref's top_vals[1:])
      if (lane == 0 && round >= 1 && round <= topn) {
        out[round - 1]        = bv / nt;       // similarity value
        out[topn + round - 1] = (float)bi;     // index, as float
      }
    }
  }
}

extern "C" void kernel_launch(void* const* d_in, const int* in_sizes, int n_in,
                              void* d_out, int out_size, void* d_ws, size_t ws_size,
                              hipStream_t stream) {
  const float* emb = (const float*)d_in[0];
  const int*   uid = (const int*)d_in[1];
  const int V    = in_sizes[0] / EMBED;
  const int topn = out_size / 2;  // 10 -> KTOP = 11 list covers it

  float* cand_val = (float*)d_ws;
  int*   cand_idx = (int*)((char*)d_ws + (size_t)NB * KTOP * sizeof(float));

  sim_pass1<<<NB, BLOCK, 0, stream>>>(emb, uid, cand_val, cand_idx, V);
  sim_pass2<<<1, BLOCK, 0, stream>>>(emb, uid, cand_val, cand_idx,
                                     (float*)d_out, topn, NB * KTOP);
}

// Round 3
// 407.266 us; speedup vs baseline: 1.1820x; 1.1820x over previous
//
#include <hip/hip_runtime.h>
#include <cmath>
#include <climits>

#define EMBED 64
#define KTOP 11          // top_n + 1 (self match included, dropped at output)
#define NB   512         // pass1 blocks: 2/CU x 256 CU, all resident
#define BLOCK1 128       // 2 waves -> 2 x 2 x 16KB = 64KB static LDS
#define NW1  (BLOCK1 / 64)
#define BLOCK2 256
#define NW2  (BLOCK2 / 64)
#define TILE_BYTES 16384 // 64 rows x 256 B

typedef const __attribute__((address_space(1))) void gv_t;
typedef __attribute__((address_space(3))) void lv_t;

// Insert (v,i) into per-thread sorted top-KTOP list (desc value, asc index).
__device__ __forceinline__ void topk_insert(float (&vals)[KTOP], int (&idxs)[KTOP],
                                            float v, int i) {
  float last = vals[KTOP - 1];
  if (v < last) return;
  if (v == last && i >= idxs[KTOP - 1]) return;
  float cv = v; int ci = i;
#pragma unroll
  for (int j = 0; j < KTOP; ++j) {
    bool better = (cv > vals[j]) || (cv == vals[j] && ci < idxs[j]);
    if (better) {
      float tv = vals[j]; int ti = idxs[j];
      vals[j] = cv; idxs[j] = ci;
      cv = tv; ci = ti;
    }
  }
}

// Merge 64 lanes' sorted top-KTOP lists into wave top-KTOP, written to LDS.
__device__ __forceinline__ void wave_merge(float (&vals)[KTOP], int (&idxs)[KTOP],
                                           float* wv, int* wi, int lane) {
#pragma unroll
  for (int round = 0; round < KTOP; ++round) {
    float v = vals[0]; int i = idxs[0]; int l = lane;
#pragma unroll
    for (int off = 32; off > 0; off >>= 1) {
      float ov = __shfl_xor(v, off, 64);
      int   oi = __shfl_xor(i, off, 64);
      int   ol = __shfl_xor(l, off, 64);
      if (ov > v || (ov == v && oi < i)) { v = ov; i = oi; l = ol; }
    }
    if (l == lane) {  // winner pops its head
#pragma unroll
      for (int j = 0; j < KTOP - 1; ++j) { vals[j] = vals[j + 1]; idxs[j] = idxs[j + 1]; }
      vals[KTOP - 1] = -INFINITY; idxs[KTOP - 1] = INT_MAX;
    }
    if (lane == 0) { wv[round] = v; wi[round] = i; }
  }
}

// Issue 16 x 1KB global->LDS DMA for one 64-row tile. LDS dest is
// wave-uniform base; HW scatters lane i to base + i*16.
__device__ __forceinline__ void dma_tile(const char* g, size_t byteBase,
                                         int lane, char* lds) {
#pragma unroll
  for (int j = 0; j < 16; ++j) {
    __builtin_amdgcn_global_load_lds(
        (gv_t*)(g + byteBase + (size_t)j * 1024 + (size_t)lane * 16),
        (lv_t*)(lds + j * 1024), 16, 0, 0);
  }
}

__device__ __forceinline__ void dma_tile_clamped(const char* g, size_t byteBase,
                                                 int lane, char* lds, size_t maxOff) {
#pragma unroll
  for (int j = 0; j < 16; ++j) {
    size_t off = byteBase + (size_t)j * 1024 + (size_t)lane * 16;
    if (off > maxOff) off = maxOff;
    __builtin_amdgcn_global_load_lds(
        (gv_t*)(g + off), (lv_t*)(lds + j * 1024), 16, 0, 0);
  }
}

__global__ __launch_bounds__(BLOCK1) void sim_pass1(
    const float* __restrict__ emb, const int* __restrict__ user_id,
    float* __restrict__ cand_val, int* __restrict__ cand_idx, int V) {
  __shared__ __align__(16) char smem[2 * NW1 * TILE_BYTES];  // 64 KB

  const int lane = threadIdx.x & 63;
  const int wid  = threadIdx.x >> 6;
  const int uid  = *user_id;

  // Target row, pre-rotated per lane: tv[j] = target chunk (j+lane)&15.
  // (4 cache lines, read once per lane -> negligible.)
  const float4* trow = (const float4*)(emb + (size_t)uid * EMBED);
  float4 tv[16];
#pragma unroll
  for (int j = 0; j < 16; ++j) tv[j] = trow[(j + lane) & 15];

  float vals[KTOP]; int idxs[KTOP];
#pragma unroll
  for (int j = 0; j < KTOP; ++j) { vals[j] = -INFINITY; idxs[j] = INT_MAX; }

  const int gw = blockIdx.x * NW1 + wid;
  const int nW = NB * NW1;
  const int nTiles = (V + 63) >> 6;
  const char* g = (const char*)emb;
  const size_t maxOff = (size_t)V * 256 - 16;
  char* myLds = smem + wid * (2 * TILE_BYTES);

  int p = 0;
  int tile = gw;
  if (tile < nTiles) {
    if (((size_t)tile * 64 + 64) * 256 - 16 <= maxOff + 0)  // full tile in range
      dma_tile(g, (size_t)tile << 14, lane, myLds);
    else
      dma_tile_clamped(g, (size_t)tile << 14, lane, myLds, maxOff);
  }

  for (; tile < nTiles; tile += nW) {
    const int next = tile + nW;
    const bool pf = next < nTiles;
    if (pf) {
      char* nb = myLds + ((p ^ 1) * TILE_BYTES);
      if ((size_t)(next + 1) * 64 * 256 - 16 <= maxOff)
        dma_tile(g, (size_t)next << 14, lane, nb);
      else
        dma_tile_clamped(g, (size_t)next << 14, lane, nb, maxOff);
      asm volatile("s_waitcnt vmcnt(16)" ::: "memory");  // tile's 16 loads done
    } else {
      asm volatile("s_waitcnt vmcnt(0)" ::: "memory");
    }

    // Serial per-lane row reduction; chunk order rotated by lane so each
    // ds_read_b128 spreads 8 dwords/bank (the LDS floor) instead of 64/4-banks.
    const char* lb = myLds + p * TILE_BYTES + lane * 256;
    float dot = 0.f, nr = 0.f;
#pragma unroll
    for (int j = 0; j < 16; ++j) {
      const int c = (j + lane) & 15;
      float4 v = *(const float4*)(lb + c * 16);
      float4 t = tv[j];
      dot = fmaf(v.x, t.x, dot); dot = fmaf(v.y, t.y, dot);
      dot = fmaf(v.z, t.z, dot); dot = fmaf(v.w, t.w, dot);
      nr  = fmaf(v.x, v.x, nr);  nr  = fmaf(v.y, v.y, nr);
      nr  = fmaf(v.z, v.z, nr);  nr  = fmaf(v.w, v.w, nr);
    }
    const int row = (tile << 6) + lane;
    if (row < V)
      topk_insert(vals, idxs, dot / sqrtf(nr), row);  // /||target|| deferred
    p ^= 1;
  }

  // Buffers are dead from here; alias merge scratch into smem.
  __syncthreads();
  float* wv = (float*)smem;
  int*   wi = (int*)(smem + NW1 * KTOP * sizeof(float));
  wave_merge(vals, idxs, &wv[wid * KTOP], &wi[wid * KTOP], lane);
  __syncthreads();

  if (wid == 0) {  // wave 0 merges NW1*KTOP entries -> block top-KTOP
    float v = (lane < NW1 * KTOP) ? wv[lane] : -INFINITY;
    int   i = (lane < NW1 * KTOP) ? wi[lane] : INT_MAX;
#pragma unroll
    for (int round = 0; round < KTOP; ++round) {
      float bv = v; int bi = i; int bl = lane;
#pragma unroll
      for (int off = 32; off > 0; off >>= 1) {
        float ov = __shfl_xor(bv, off, 64);
        int   oi = __shfl_xor(bi, off, 64);
        int   ol = __shfl_xor(bl, off, 64);
        if (ov > bv || (ov == bv && oi < bi)) { bv = ov; bi = oi; bl = ol; }
      }
      if (bl == lane) { v = -INFINITY; i = INT_MAX; }
      if (lane == 0) {
        cand_val[blockIdx.x * KTOP + round] = bv;
        cand_idx[blockIdx.x * KTOP + round] = bi;
      }
    }
  }
}

__global__ __launch_bounds__(BLOCK2) void sim_pass2(
    const float* __restrict__ emb, const int* __restrict__ user_id,
    const float* __restrict__ cand_val, const int* __restrict__ cand_idx,
    float* __restrict__ out, int topn, int ncand) {
  __shared__ float wv[NW2 * KTOP];
  __shared__ int   wi[NW2 * KTOP];
  __shared__ float s_nt;

  const int lane = threadIdx.x & 63;
  const int wid  = threadIdx.x >> 6;

  if (wid == 0) {  // ||target|| on wave 0
    const int uid = *user_id;
    float x = (lane < EMBED) ? emb[(size_t)uid * EMBED + lane] : 0.f;
    float s = x * x;
#pragma unroll
    for (int off = 32; off > 0; off >>= 1) s += __shfl_xor(s, off, 64);
    if (lane == 0) s_nt = sqrtf(s);
  }

  float vals[KTOP]; int idxs[KTOP];
#pragma unroll
  for (int j = 0; j < KTOP; ++j) { vals[j] = -INFINITY; idxs[j] = INT_MAX; }

  for (int c = threadIdx.x; c < ncand; c += BLOCK2)
    topk_insert(vals, idxs, cand_val[c], cand_idx[c]);

  wave_merge(vals, idxs, &wv[wid * KTOP], &wi[wid * KTOP], lane);
  __syncthreads();

  if (wid == 0) {
    float v = (lane < NW2 * KTOP) ? wv[lane] : -INFINITY;
    int   i = (lane < NW2 * KTOP) ? wi[lane] : INT_MAX;
    const float nt = s_nt;
#pragma unroll
    for (int round = 0; round < KTOP; ++round) {
      float bv = v; int bi = i; int bl = lane;
#pragma unroll
      for (int off = 32; off > 0; off >>= 1) {
        float ov = __shfl_xor(bv, off, 64);
        int   oi = __shfl_xor(bi, off, 64);
        int   ol = __shfl_xor(bl, off, 64);
        if (ov > bv || (ov == bv && oi < bi)) { bv = ov; bi = oi; bl = ol; }
      }
      if (bl == lane) { v = -INFINITY; i = INT_MAX; }
      // round 0 is the self match -> dropped (matches ref's top_vals[1:])
      if (lane == 0 && round >= 1 && round <= topn) {
        out[round - 1]        = bv / nt;       // similarity value
        out[topn + round - 1] = (float)bi;     // index, as float
      }
    }
  }
}

extern "C" void kernel_launch(void* const* d_in, const int* in_sizes, int n_in,
                              void* d_out, int out_size, void* d_ws, size_t ws_size,
                              hipStream_t stream) {
  const float* emb = (const float*)d_in[0];
  const int*   uid = (const int*)d_in[1];
  const int V    = in_sizes[0] / EMBED;
  const int topn = out_size / 2;  // 10 -> KTOP = 11 covers it

  float* cand_val = (float*)d_ws;
  int*   cand_idx = (int*)((char*)d_ws + (size_t)NB * KTOP * sizeof(float));

  sim_pass1<<<NB, BLOCK1, 0, stream>>>(emb, uid, cand_val, cand_idx, V);
  sim_pass2<<<1, BLOCK2, 0, stream>>>(emb, uid, cand_val, cand_idx,
                                      (float*)d_out, topn, NB * KTOP);
}

// Round 4
// 402.706 us; speedup vs baseline: 1.1954x; 1.0113x over previous
//
#include <hip/hip_runtime.h>
#include <cmath>
#include <climits>

#define EMBED 64
#define KTOP 11          // top_n + 1 (self match included, dropped at output)
#define NB   512         // pass1 blocks: 2/CU x 256 CU, all resident
#define BLOCK1 256       // 4 waves; 2 buf x 4 waves x 8KB = 64KB static LDS
#define NW1  (BLOCK1 / 64)
#define BLOCK2 256
#define NW2  (BLOCK2 / 64)
#define TROWS 32         // rows per tile
#define TILE_BYTES (TROWS * 256)   // 8 KB
#define TILE_DMA   (TILE_BYTES / 1024)  // 8 x 1KB DMA instructions

typedef const __attribute__((address_space(1))) void gv_t;
typedef __attribute__((address_space(3))) void lv_t;

// Insert (v,i) into per-thread sorted top-KTOP list (desc value, asc index).
__device__ __forceinline__ void topk_insert(float (&vals)[KTOP], int (&idxs)[KTOP],
                                            float v, int i) {
  float last = vals[KTOP - 1];
  if (v < last) return;
  if (v == last && i >= idxs[KTOP - 1]) return;
  float cv = v; int ci = i;
#pragma unroll
  for (int j = 0; j < KTOP; ++j) {
    bool better = (cv > vals[j]) || (cv == vals[j] && ci < idxs[j]);
    if (better) {
      float tv = vals[j]; int ti = idxs[j];
      vals[j] = cv; idxs[j] = ci;
      cv = tv; ci = ti;
    }
  }
}

// Merge 64 lanes' sorted top-KTOP lists into wave top-KTOP, written to LDS.
__device__ __forceinline__ void wave_merge(float (&vals)[KTOP], int (&idxs)[KTOP],
                                           float* wv, int* wi, int lane) {
#pragma unroll
  for (int round = 0; round < KTOP; ++round) {
    float v = vals[0]; int i = idxs[0]; int l = lane;
#pragma unroll
    for (int off = 32; off > 0; off >>= 1) {
      float ov = __shfl_xor(v, off, 64);
      int   oi = __shfl_xor(i, off, 64);
      int   ol = __shfl_xor(l, off, 64);
      if (ov > v || (ov == v && oi < i)) { v = ov; i = oi; l = ol; }
    }
    if (l == lane) {  // winner pops its head
#pragma unroll
      for (int j = 0; j < KTOP - 1; ++j) { vals[j] = vals[j + 1]; idxs[j] = idxs[j + 1]; }
      vals[KTOP - 1] = -INFINITY; idxs[KTOP - 1] = INT_MAX;
    }
    if (lane == 0) { wv[round] = v; wi[round] = i; }
  }
}

// Issue TILE_DMA x 1KB global->LDS DMA for one 32-row tile (contiguous).
__device__ __forceinline__ void dma_tile(const char* g, size_t byteBase,
                                         int lane, char* lds) {
#pragma unroll
  for (int j = 0; j < TILE_DMA; ++j) {
    __builtin_amdgcn_global_load_lds(
        (gv_t*)(g + byteBase + (size_t)j * 1024 + (size_t)lane * 16),
        (lv_t*)(lds + j * 1024), 16, 0, 0);
  }
}

__device__ __forceinline__ void dma_tile_clamped(const char* g, size_t byteBase,
                                                 int lane, char* lds, size_t maxOff) {
#pragma unroll
  for (int j = 0; j < TILE_DMA; ++j) {
    size_t off = byteBase + (size_t)j * 1024 + (size_t)lane * 16;
    if (off > maxOff) off = maxOff;
    __builtin_amdgcn_global_load_lds(
        (gv_t*)(g + off), (lv_t*)(lds + j * 1024), 16, 0, 0);
  }
}

__global__ __launch_bounds__(BLOCK1, 2) void sim_pass1(
    const float* __restrict__ emb, const int* __restrict__ user_id,
    float* __restrict__ cand_val, int* __restrict__ cand_idx, int V) {
  __shared__ __align__(16) char smem[2 * NW1 * TILE_BYTES];  // 64 KB

  const int lane = threadIdx.x & 63;
  const int wid  = threadIdx.x >> 6;
  const int uid  = *user_id;
  const int row  = lane & 31;        // my row within tile
  const int half = lane >> 5;        // which 8-chunk half of the row

  // Target chunks for my half-row, pre-rotated per lane:
  // tv[j] = target chunk half*8 + ((j+lane)&7)
  const float4* trow = (const float4*)(emb + (size_t)uid * EMBED);
  float4 tv[8];
#pragma unroll
  for (int j = 0; j < 8; ++j) tv[j] = trow[half * 8 + ((j + lane) & 7)];

  float vals[KTOP]; int idxs[KTOP];
#pragma unroll
  for (int j = 0; j < KTOP; ++j) { vals[j] = -INFINITY; idxs[j] = INT_MAX; }

  const int gw = blockIdx.x * NW1 + wid;
  const int nW = NB * NW1;
  const int nTiles = (V + TROWS - 1) / TROWS;
  const char* g = (const char*)emb;
  const size_t maxOff = (size_t)V * 256 - 16;
  char* myLds = smem + wid * (2 * TILE_BYTES);

  int p = 0;
  int tile = gw;
  if (tile < nTiles) {
    if ((size_t)(tile + 1) * TILE_BYTES - 16 <= maxOff)
      dma_tile(g, (size_t)tile * TILE_BYTES, lane, myLds);
    else
      dma_tile_clamped(g, (size_t)tile * TILE_BYTES, lane, myLds, maxOff);
  }

  int par = 0;  // insert-duty parity, alternates so both halves build lists
  for (; tile < nTiles; tile += nW, par ^= 1) {
    const int next = tile + nW;
    if (next < nTiles) {
      char* nb = myLds + ((p ^ 1) * TILE_BYTES);
      if ((size_t)(next + 1) * TILE_BYTES - 16 <= maxOff)
        dma_tile(g, (size_t)next * TILE_BYTES, lane, nb);
      else
        dma_tile_clamped(g, (size_t)next * TILE_BYTES, lane, nb, maxOff);
      asm volatile("s_waitcnt vmcnt(8)" ::: "memory");  // current tile done
    } else {
      asm volatile("s_waitcnt vmcnt(0)" ::: "memory");
    }

    // Half-row per lane: 8 rotated ds_read_b128 + 64 FMA, then one
    // xor-32 combine. Rotation keeps each bank at its structural minimum.
    const char* lb = myLds + p * TILE_BYTES + row * 256 + half * 128;
    float dot = 0.f, nr = 0.f;
#pragma unroll
    for (int j = 0; j < 8; ++j) {
      float4 v = *(const float4*)(lb + ((j + lane) & 7) * 16);
      float4 t = tv[j];
      dot = fmaf(v.x, t.x, dot); dot = fmaf(v.y, t.y, dot);
      dot = fmaf(v.z, t.z, dot); dot = fmaf(v.w, t.w, dot);
      nr  = fmaf(v.x, v.x, nr);  nr  = fmaf(v.y, v.y, nr);
      nr  = fmaf(v.z, v.z, nr);  nr  = fmaf(v.w, v.w, nr);
    }
    dot += __shfl_xor(dot, 32, 64);
    nr  += __shfl_xor(nr,  32, 64);

    const int r = tile * TROWS + row;
    if (half == par && r < V)
      topk_insert(vals, idxs, dot / sqrtf(nr), r);  // /||target|| deferred
    p ^= 1;
  }

  // Buffers dead; alias merge scratch into smem.
  __syncthreads();
  float* wv = (float*)smem;
  int*   wi = (int*)(smem + NW1 * KTOP * sizeof(float));
  wave_merge(vals, idxs, &wv[wid * KTOP], &wi[wid * KTOP], lane);
  __syncthreads();

  if (wid == 0) {  // wave 0 merges NW1*KTOP entries -> block top-KTOP
    float v = (lane < NW1 * KTOP) ? wv[lane] : -INFINITY;
    int   i = (lane < NW1 * KTOP) ? wi[lane] : INT_MAX;
#pragma unroll
    for (int round = 0; round < KTOP; ++round) {
      float bv = v; int bi = i; int bl = lane;
#pragma unroll
      for (int off = 32; off > 0; off >>= 1) {
        float ov = __shfl_xor(bv, off, 64);
        int   oi = __shfl_xor(bi, off, 64);
        int   ol = __shfl_xor(bl, off, 64);
        if (ov > bv || (ov == bv && oi < bi)) { bv = ov; bi = oi; bl = ol; }
      }
      if (bl == lane) { v = -INFINITY; i = INT_MAX; }
      if (lane == 0) {
        cand_val[blockIdx.x * KTOP + round] = bv;
        cand_idx[blockIdx.x * KTOP + round] = bi;
      }
    }
  }
}

__global__ __launch_bounds__(BLOCK2) void sim_pass2(
    const float* __restrict__ emb, const int* __restrict__ user_id,
    const float* __restrict__ cand_val, const int* __restrict__ cand_idx,
    float* __restrict__ out, int topn, int ncand) {
  __shared__ float wv[NW2 * KTOP];
  __shared__ int   wi[NW2 * KTOP];
  __shared__ float s_nt;

  const int lane = threadIdx.x & 63;
  const int wid  = threadIdx.x >> 6;

  if (wid == 0) {  // ||target|| on wave 0
    const int uid = *user_id;
    float x = (lane < EMBED) ? emb[(size_t)uid * EMBED + lane] : 0.f;
    float s = x * x;
#pragma unroll
    for (int off = 32; off > 0; off >>= 1) s += __shfl_xor(s, off, 64);
    if (lane == 0) s_nt = sqrtf(s);
  }

  float vals[KTOP]; int idxs[KTOP];
#pragma unroll
  for (int j = 0; j < KTOP; ++j) { vals[j] = -INFINITY; idxs[j] = INT_MAX; }

  for (int c = threadIdx.x; c < ncand; c += BLOCK2)
    topk_insert(vals, idxs, cand_val[c], cand_idx[c]);

  wave_merge(vals, idxs, &wv[wid * KTOP], &wi[wid * KTOP], lane);
  __syncthreads();

  if (wid == 0) {
    float v = (lane < NW2 * KTOP) ? wv[lane] : -INFINITY;
    int   i = (lane < NW2 * KTOP) ? wi[lane] : INT_MAX;
    const float nt = s_nt;
#pragma unroll
    for (int round = 0; round < KTOP; ++round) {
      float bv = v; int bi = i; int bl = lane;
#pragma unroll
      for (int off = 32; off > 0; off >>= 1) {
        float ov = __shfl_xor(bv, off, 64);
        int   oi = __shfl_xor(bi, off, 64);
        int   ol = __shfl_xor(bl, off, 64);
        if (ov > bv || (ov == bv && oi < bi)) { bv = ov; bi = oi; bl = ol; }
      }
      if (bl == lane) { v = -INFINITY; i = INT_MAX; }
      // round 0 is the self match -> dropped (matches ref's top_vals[1:])
      if (lane == 0 && round >= 1 && round <= topn) {
        out[round - 1]        = bv / nt;       // similarity value
        out[topn + round - 1] = (float)bi;     // index, as float
      }
    }
  }
}

extern "C" void kernel_launch(void* const* d_in, const int* in_sizes, int n_in,
                              void* d_out, int out_size, void* d_ws, size_t ws_size,
                              hipStream_t stream) {
  const float* emb = (const float*)d_in[0];
  const int*   uid = (const int*)d_in[1];
  const int V    = in_sizes[0] / EMBED;
  const int topn = out_size / 2;  // 10 -> KTOP = 11 covers it

  float* cand_val = (float*)d_ws;
  int*   cand_idx = (int*)((char*)d_ws + (size_t)NB * KTOP * sizeof(float));

  sim_pass1<<<NB, BLOCK1, 0, stream>>>(emb, uid, cand_val, cand_idx, V);
  sim_pass2<<<1, BLOCK2, 0, stream>>>(emb, uid, cand_val, cand_idx,
                                      (float*)d_out, topn, NB * KTOP);
}